// Round 5
// baseline (333.670 us; speedup 1.0000x reference)
//
#include <hip/hip_runtime.h>

typedef __bf16 bf16_t;
typedef __attribute__((ext_vector_type(8))) __bf16 bf16x8;
typedef __attribute__((ext_vector_type(4))) float f32x4;
typedef __attribute__((ext_vector_type(8))) unsigned short u16x8;

#define LHS 520   // H LDS row stride in shorts (16B aligned, spreads b128 starts)

// ---------------- dtype detect: 1 = bf16 inputs, 0 = fp32 inputs.
__global__ void detect_dtype(const unsigned short* __restrict__ ct, int* __restrict__ flag) {
    if (threadIdx.x == 0 && blockIdx.x == 0) {
        int ok = 1;
        for (int i = 0; i < 16; i++) {
            int e = (ct[256 + i] >> 7) & 0xFF;
            ok &= (e >= 80 && e <= 126) ? 1 : 0;
        }
        *flag = ok;
    }
}

// ---------------- scan: wave-aggregated partition (1 atomic per wave per bucket)
__global__ void scan_rows(const int* __restrict__ lvl2, const int* __restrict__ lvl1,
                          const int* __restrict__ lvl0, const int* __restrict__ third,
                          int* __restrict__ lists, int* __restrict__ cnts, int* __restrict__ inv) {
    int r = blockIdx.x * 256 + threadIdx.x;   // grid covers exactly 28672
    int slot, lr, base_t, base_b;
    const int* lvl;
    if (r < 16384)      { slot = 0; lr = r;         lvl = lvl2; base_t = 0;     base_b = 16384; }
    else if (r < 24576) { slot = 1; lr = r - 16384; lvl = lvl1; base_t = 32768; base_b = 40960; }
    else                { slot = 2; lr = r - 24576; lvl = lvl0; base_t = 49152; base_b = 53248; }
    int node = lvl[lr];
    int tern = third[node] >= 0 ? 1 : 0;
    if (slot == 0)      inv[node] = lr;
    else if (slot == 1) inv[node] = 16384 + lr;

    unsigned long long bt = __ballot(tern);
    unsigned long long bb = __ballot(!tern);
    int lane = threadIdx.x & 63;
    unsigned long long ltm = (1ull << lane) - 1ull;
    int post = __popcll(bt & ltm), posb = __popcll(bb & ltm);
    int baseT = 0, baseB = 0;
    if (lane == 0) {
        baseT = atomicAdd(&cnts[slot * 2 + 1], __popcll(bt));
        baseB = atomicAdd(&cnts[slot * 2 + 0], __popcll(bb));
    }
    baseT = __shfl(baseT, 0, 64);
    baseB = __shfl(baseB, 0, 64);
    lists[tern ? (base_t + baseT + post) : (base_b + baseB + posb)] = lr;
}

// ---------------- pack weights [K][N] -> MFMA frag order [kc][ntile][lane][8]
__device__ __forceinline__ void packfrag(const void* __restrict__ src, bf16_t* __restrict__ dst,
                                         int e, int Nmask, int Nshift, int isbf) {
    bf16_t v = isbf ? ((const bf16_t*)src)[e] : (bf16_t)((const float*)src)[e];
    int n = e & Nmask, k = e >> Nshift;
    int kc = k >> 5, kq = (k >> 3) & 3, j = k & 7;
    int ntile = n >> 4, c = n & 15;
    int NT = 1 << (Nshift - 4);
    dst[((((size_t)kc * NT + ntile) * 64) + (kq * 16 + c)) * 8 + j] = v;
}

// one kernel for all weight packs + ct/op bf16 conversion (cuts dispatch count)
__global__ void pack_all(const void* __restrict__ W1t, const void* __restrict__ W1b,
                         const void* __restrict__ W2t, const void* __restrict__ W2b,
                         const void* __restrict__ ct, const void* __restrict__ op,
                         bf16_t* __restrict__ W1tf, bf16_t* __restrict__ W1bf,
                         bf16_t* __restrict__ W2tf, bf16_t* __restrict__ W2bf,
                         bf16_t* __restrict__ ctb, bf16_t* __restrict__ opb,
                         const int* __restrict__ flagp) {
    int e = blockIdx.x * 256 + threadIdx.x;
    int isbf = *flagp;
    if (e < 524288)       packfrag(W1t, W1tf, e, 511, 9, isbf);
    else if (e < 917504)  packfrag(W1b, W1bf, e - 524288, 511, 9, isbf);
    else if (e < 1048576) packfrag(W2t, W2tf, e - 917504, 255, 8, isbf);
    else if (e < 1179648) packfrag(W2b, W2bf, e - 1048576, 255, 8, isbf);
    else if (e < 1691648) {
        int i = e - 1179648;   // 2000*256 comp_table -> bf16
        ctb[i] = isbf ? ((const bf16_t*)ct)[i] : (bf16_t)((const float*)ct)[i];
    } else if (e < 1695744) {
        int i = e - 1691648;   // 16*256 op_table -> bf16
        opb[i] = isbf ? ((const bf16_t*)op)[i] : (bf16_t)((const float*)op)[i];
    }
}

__device__ __forceinline__ void load8f(const bf16_t* ne2, const void* ct, int isbf,
                                       int invn, int cidn, int q, float* o) {
    if (invn >= 0) {
        bf16x8 v = *(const bf16x8*)(ne2 + (size_t)invn * 256 + q);
        for (int z = 0; z < 8; z++) o[z] = (float)v[z];
    } else if (isbf) {
        bf16x8 v = *(const bf16x8*)((const bf16_t*)ct + (size_t)cidn * 256 + q);
        for (int z = 0; z < 8; z++) o[z] = (float)v[z];
    } else {
        const float* fp = (const float*)ct + (size_t)cidn * 256 + q;
        f32x4 a = *(const f32x4*)fp, b = *(const f32x4*)(fp + 4);
        for (int z = 0; z < 4; z++) { o[z] = a[z]; o[z + 4] = b[z]; }
    }
}

__device__ __forceinline__ float ldparam(const void* p, int i, int isbf) {
    return isbf ? (float)((const bf16_t*)p)[i] : ((const float*)p)[i];
}

// ---------------- fused level kernel v2: barrier-free GEMMs, B/A frags direct global->VGPR
__global__ __launch_bounds__(256, 2) void fused_level(
    const int* __restrict__ list_t, const int* __restrict__ list_b,
    const int* __restrict__ cntpair, const int* __restrict__ lvl_idx,
    const int* __restrict__ op_ids, const int* __restrict__ lch,
    const int* __restrict__ rch, const int* __restrict__ tch,
    bf16_t* __restrict__ ne2, const bf16_t* __restrict__ opb,
    const bf16_t* __restrict__ ctb, const void* __restrict__ ct,
    const int* __restrict__ cid, const int* __restrict__ inv,
    const int* __restrict__ flagp,
    const bf16_t* __restrict__ W1tf, const void* __restrict__ b1t,
    const bf16_t* __restrict__ W2tf, const void* __restrict__ b2t,
    const bf16_t* __restrict__ W1bf, const void* __restrict__ b1b,
    const bf16_t* __restrict__ W2bf, const void* __restrict__ b2b,
    const void* __restrict__ gma, const void* __restrict__ bta,
    int slotBase, void* __restrict__ out)
{
    __shared__ __align__(16) unsigned short Hbuf[32 * LHS]; // 33280 B; doubles as Rf float[32][260]
    __shared__ float scr[320];                              // LN partials

    const int tid = threadIdx.x;
    const int w = tid >> 6, lane = tid & 63, cc = lane & 15, qq = lane >> 4;
    const int cnt_t = cntpair[1], cnt_b = cntpair[0];
    const int blocks_t = (cnt_t + 31) >> 5;
    int tern, base, cnt;
    const int* list;
    const bf16_t *W1f, *W2f;
    const void *b1, *b2;
    if ((int)blockIdx.x < blocks_t) {
        tern = 1; list = list_t; base = blockIdx.x * 32; cnt = cnt_t;
        W1f = W1tf; b1 = b1t; W2f = W2tf; b2 = b2t;
    } else {
        tern = 0; list = list_b; base = (blockIdx.x - blocks_t) * 32; cnt = cnt_b;
        if (base >= cnt) return;
        W1f = W1bf; b1 = b1b; W2f = W2bf; b2 = b2b;
    }
    const int act = min(32, cnt - base);
    const int isbf = *flagp;
    const int P = tern ? 4 : 3;

    // per-lane A-row source pointers for rows cc (m=0) and cc+16 (m=1), pieces op/l/r/t
    const bf16_t* aptr[2][4];
#pragma unroll
    for (int m = 0; m < 2; m++) {
        int lr = list[base + min(m * 16 + cc, act - 1)];
        int nd = lvl_idx[lr];
        aptr[m][0] = opb + op_ids[nd] * 256;
        int ch0 = lch[nd], ch1 = rch[nd];
        int ch2 = tern ? tch[nd] : ch0;
        int chs[3] = {ch0, ch1, ch2};
#pragma unroll
        for (int s = 0; s < 3; s++) {
            int iv = inv[chs[s]];
            aptr[m][s + 1] = iv >= 0 ? ne2 + (size_t)iv * 256 : ctb + (size_t)cid[chs[s]] * 256;
        }
    }

    const f32x4 zf = {0.f, 0.f, 0.f, 0.f};
    f32x4 acc1[2][8];
#pragma unroll
    for (int m = 0; m < 2; m++) for (int j = 0; j < 8; j++) acc1[m][j] = zf;

    // ---------- GEMM1: [32 x K1] @ [K1 x 512], no LDS, no barriers
#pragma unroll
    for (int p = 0; p < 4; p++) {
        if (p < P) {
#pragma unroll
            for (int k8 = 0; k8 < 8; k8++) {
                const int kc = p * 8 + k8;
                bf16x8 a0 = *(const bf16x8*)(aptr[0][p] + k8 * 32 + qq * 8);
                bf16x8 a1 = *(const bf16x8*)(aptr[1][p] + k8 * 32 + qq * 8);
#pragma unroll
                for (int j = 0; j < 8; j++) {
                    bf16x8 bv = *(const bf16x8*)(W1f + (((size_t)kc * 32 + (w + 4 * j)) * 64 + lane) * 8);
                    acc1[0][j] = __builtin_amdgcn_mfma_f32_16x16x32_bf16(a0, bv, acc1[0][j], 0, 0, 0);
                    acc1[1][j] = __builtin_amdgcn_mfma_f32_16x16x32_bf16(a1, bv, acc1[1][j], 0, 0, 0);
                }
            }
        }
    }

    // ---------- bias + exact GELU -> H in LDS [32][512] (stride 520)
    {
        bf16_t* Hl = (bf16_t*)Hbuf;
#pragma unroll
        for (int m = 0; m < 2; m++) for (int j = 0; j < 8; j++) {
            int col = (w + 4 * j) * 16 + cc;
            float bb = ldparam(b1, col, isbf);
#pragma unroll
            for (int r = 0; r < 4; r++) {
                float v = acc1[m][j][r] + bb;
                float h = 0.5f * v * (1.0f + erff(v * 0.70710678118654752f));
                Hl[(m * 16 + qq * 4 + r) * LHS + col] = (bf16_t)h;
            }
        }
    }
    __syncthreads();

    // ---------- GEMM2: [32 x 512] @ [512 x 256]; A from LDS, B direct global->VGPR
    f32x4 acc2[2][4];
#pragma unroll
    for (int m = 0; m < 2; m++) for (int j = 0; j < 4; j++) acc2[m][j] = zf;
#pragma unroll
    for (int kc = 0; kc < 16; kc++) {
        bf16x8 a0 = *(const bf16x8*)((const bf16_t*)Hbuf + cc * LHS + kc * 32 + qq * 8);
        bf16x8 a1 = *(const bf16x8*)((const bf16_t*)Hbuf + (16 + cc) * LHS + kc * 32 + qq * 8);
#pragma unroll
        for (int j = 0; j < 4; j++) {
            bf16x8 bv = *(const bf16x8*)(W2f + (((size_t)kc * 16 + (w + 4 * j)) * 64 + lane) * 8);
            acc2[0][j] = __builtin_amdgcn_mfma_f32_16x16x32_bf16(a0, bv, acc2[0][j], 0, 0, 0);
            acc2[1][j] = __builtin_amdgcn_mfma_f32_16x16x32_bf16(a1, bv, acc2[1][j], 0, 0, 0);
        }
    }
    __syncthreads();   // H reads done before Rf overwrites Hbuf

    // ---------- residual gather -> Hbuf as float[32][260]
    const int ms = tid >> 3, gs = tid & 7;
    int sInv[3], sCid[3];
    {
        int lrS = list[base + min(ms, act - 1)];
        int ndS = lvl_idx[lrS];
        int sn[3] = {lch[ndS], rch[ndS], tern ? tch[ndS] : lch[ndS]};
#pragma unroll
        for (int s = 0; s < 3; s++) {
            sInv[s] = inv[sn[s]];
            sCid[s] = sInv[s] < 0 ? cid[sn[s]] : 0;
        }
    }
    {
        float* Rf = (float*)Hbuf;
        int colb = gs * 32;
        for (int i = 0; i < 4; i++) {
            int q = colb + i * 8;
            float lv[8], rv[8], tv[8];
            load8f(ne2, ct, isbf, sInv[0], sCid[0], q, lv);
            load8f(ne2, ct, isbf, sInv[1], sCid[1], q, rv);
            if (tern) load8f(ne2, ct, isbf, sInv[2], sCid[2], q, tv);
            f32x4 s0, s1;
            if (tern) {
                for (int z = 0; z < 4; z++) {
                    s0[z] = (lv[z] + rv[z] + tv[z]) * (1.0f / 3.0f);
                    s1[z] = (lv[z + 4] + rv[z + 4] + tv[z + 4]) * (1.0f / 3.0f);
                }
            } else {
                for (int z = 0; z < 4; z++) {
                    s0[z] = lv[z] + rv[z];
                    s1[z] = lv[z + 4] + rv[z + 4];
                }
            }
            *(f32x4*)(Rf + ms * 260 + q) = s0;
            *(f32x4*)(Rf + ms * 260 + q + 4) = s1;
        }
    }
    __syncthreads();

    // ---------- x = gemm2 + b2 + R ; LayerNorm over 256 cols per row
    float b2f[4], gf[4], btf[4];
#pragma unroll
    for (int j = 0; j < 4; j++) {
        int col = (w + 4 * j) * 16 + cc;
        b2f[j] = ldparam(b2, col, isbf);
        gf[j] = ldparam(gma, col, isbf);
        btf[j] = ldparam(bta, col, isbf);
    }
    float* partS = scr;           // [4][32]
    float* partQ = scr + 128;     // [4][32]
    float* muA   = scr + 256;     // [32]
    float* rsA   = scr + 288;     // [32]
    const float* Rf = (const float*)Hbuf;

#pragma unroll
    for (int m = 0; m < 2; m++) for (int r = 0; r < 4; r++) {
        int row = m * 16 + qq * 4 + r;
        float ps = 0.f, pq = 0.f;
#pragma unroll
        for (int j = 0; j < 4; j++) {
            int col = (w + 4 * j) * 16 + cc;
            float x = acc2[m][j][r] + b2f[j] + Rf[row * 260 + col];
            acc2[m][j][r] = x;
            ps += x; pq += x * x;
        }
        for (int d = 1; d < 16; d <<= 1) {
            ps += __shfl_xor(ps, d, 64);
            pq += __shfl_xor(pq, d, 64);
        }
        if (cc == 0) { partS[w * 32 + row] = ps; partQ[w * 32 + row] = pq; }
    }
    __syncthreads();
    if (tid < 32) {
        float s  = partS[tid] + partS[32 + tid] + partS[64 + tid] + partS[96 + tid];
        float sq = partQ[tid] + partQ[32 + tid] + partQ[64 + tid] + partQ[96 + tid];
        float mu = s * (1.0f / 256.0f);
        float var = sq * (1.0f / 256.0f) - mu * mu;
        muA[tid] = mu;
        rsA[tid] = rsqrtf(fmaxf(var, 0.0f) + 1e-5f);
    }
    __syncthreads();

#pragma unroll
    for (int m = 0; m < 2; m++) for (int r = 0; r < 4; r++) {
        int row = m * 16 + qq * 4 + r;
        if (row >= act) continue;
        float mu = muA[row], rs = rsA[row];
        int lr2 = list[base + row];
#pragma unroll
        for (int j = 0; j < 4; j++) {
            int col = (w + 4 * j) * 16 + cc;
            float y = (acc2[m][j][r] - mu) * rs * gf[j] + btf[j];
            if (out) {
                if (isbf) ((bf16_t*)out)[(size_t)lr2 * 256 + col] = (bf16_t)y;
                else      ((float*)out)[(size_t)lr2 * 256 + col] = y;
            } else {
                ne2[(size_t)(slotBase + lr2) * 256 + col] = (bf16_t)y;
            }
        }
    }
}

extern "C" void kernel_launch(void* const* d_in, const int* in_sizes, int n_in,
                              void* d_out, int out_size, void* d_ws, size_t ws_size,
                              hipStream_t stream) {
    const int* cid    = (const int*)d_in[0];
    const int* opids  = (const int*)d_in[1];
    const int* lch    = (const int*)d_in[2];
    const int* rch    = (const int*)d_in[3];
    const int* tch    = (const int*)d_in[4];
    const int* lvl2   = (const int*)d_in[5];
    const int* lvl1   = (const int*)d_in[6];
    const int* lvl0   = (const int*)d_in[7];
    const void* comp_table = d_in[8];
    const void* op_table   = d_in[9];
    const void* W1b = d_in[10];
    const void* b1b = d_in[11];
    const void* W2b = d_in[12];
    const void* b2b = d_in[13];
    const void* W1t = d_in[14];
    const void* b1t = d_in[15];
    const void* W2t = d_in[16];
    const void* b2t = d_in[17];
    const void* gma = d_in[18];
    const void* bta = d_in[19];

    char* wsp = (char*)d_ws;
    bf16_t* ne2  = (bf16_t*)wsp;                 size_t off = 12582912; // 24576*256*2
    bf16_t* opb  = (bf16_t*)(wsp + off);         off += 8192;           // 16*256*2
    bf16_t* ctb  = (bf16_t*)(wsp + off);         off += 1024000;        // 2000*256*2
    bf16_t* W1tf = (bf16_t*)(wsp + off);         off += 1048576;        // 1024*512*2
    bf16_t* W1bf = (bf16_t*)(wsp + off);         off += 786432;         // 768*512*2
    bf16_t* W2tf = (bf16_t*)(wsp + off);         off += 262144;         // 512*256*2
    bf16_t* W2bf = (bf16_t*)(wsp + off);         off += 262144;
    int* inv   = (int*)(wsp + off);              off += 262144;         // 65536*4
    int* lists = (int*)(wsp + off);              off += 229376;         // 57344*4
    int* cnts  = (int*)(wsp + off);              off += 64;             // total ~15.7 MB
    int* flag  = cnts + 8;

    hipMemsetAsync(cnts, 0, 64, stream);
    hipMemsetAsync(inv, 0xFF, 262144, stream);
    detect_dtype<<<1, 64, 0, stream>>>((const unsigned short*)comp_table, flag);
    scan_rows<<<112, 256, 0, stream>>>(lvl2, lvl1, lvl0, tch, lists, cnts, inv);
    pack_all<<<6624, 256, 0, stream>>>(W1t, W1b, W2t, W2b, comp_table, op_table,
                                       W1tf, W1bf, W2tf, W2bf, ctb, opb, flag);

    // level 2: lists t @0 / b @16384, cnts slot 0 -> slots base 0
    fused_level<<<513, 256, 0, stream>>>(lists + 0, lists + 16384, cnts + 0, lvl2,
        opids, lch, rch, tch, ne2, opb, ctb, comp_table, cid, inv, flag,
        W1tf, b1t, W2tf, b2t, W1bf, b1b, W2bf, b2b, gma, bta, 0, nullptr);
    // level 1: lists t @32768 / b @40960, cnts slot 1 -> slots base 16384
    fused_level<<<257, 256, 0, stream>>>(lists + 32768, lists + 40960, cnts + 2, lvl1,
        opids, lch, rch, tch, ne2, opb, ctb, comp_table, cid, inv, flag,
        W1tf, b1t, W2tf, b2t, W1bf, b1b, W2bf, b2b, gma, bta, 16384, nullptr);
    // level 0: lists t @49152 / b @53248, cnts slot 2 -> d_out
    fused_level<<<129, 256, 0, stream>>>(lists + 49152, lists + 53248, cnts + 4, lvl0,
        opids, lch, rch, tch, ne2, opb, ctb, comp_table, cid, inv, flag,
        W1tf, b1t, W2tf, b2t, W1bf, b1b, W2bf, b2b, gma, bta, 0, d_out);
}